// Round 9
// baseline (409.654 us; speedup 1.0000x reference)
//
#include <hip/hip_runtime.h>

#define HW 192
#define DD 512
#define GG 64
#define PP 64
#define SLAB 98304  // 192*512 fp8 bytes per slab

typedef __attribute__((ext_vector_type(4))) int intx4;
typedef __attribute__((ext_vector_type(8))) int intx8;
typedef __attribute__((ext_vector_type(16))) float floatx16;

__device__ __forceinline__ unsigned short f2bf(float f) {
  unsigned int u = __float_as_uint(f);
  u += 0x7fffu + ((u >> 16) & 1u);
  return (unsigned short)(u >> 16);
}

__device__ __forceinline__ float bf2f(unsigned short u) {
  return __uint_as_float(((unsigned int)u) << 16);
}

// L2-normalize over channels -> fp8 e4m3, 32x32x64-fragment-linear ws layout:
// ws[slab][kb2(8)][R(6)][q(2)][lane(64)][16B]
//   row = R*32 + (lane&31), khalf = lane>>5,
//   bytes = channels kb2*64 + khalf*32 + q*16 .. +15 of that row.
// (r7-HW-validated operand order for mfma_scale_f32_32x32x64_f8f6f4.)
// Block = (slab, 32-pos chunk R), 512 threads.
__global__ __launch_bounds__(512, 2) void norm_kernel(
    const float* __restrict__ gal, const float* __restrict__ prob,
    unsigned char* __restrict__ ws) {
  int b = blockIdx.x;  // 0..767
  int s = b / 6;       // slab 0..127
  int R = b - s * 6;   // 0..5
  const float* in = (s < GG) ? (gal + (size_t)s * DD * HW)
                             : (prob + (size_t)(s - GG) * DD * HW);
  unsigned char* out = ws + (size_t)s * SLAB;
  int pos0 = R * 32;
  int t = threadIdx.x;

  __shared__ unsigned short T[32][524];  // 33.5 KB bf16 [pos][c], pad 524 -> <=2-way
  __shared__ float sqa[64][36];
  __shared__ float sq2[8][36];
  __shared__ float scl[32];

  {
    int cc = t >> 3;       // 0..63
    int p4 = (t & 7) * 4;  // 0,4,...,28
    float q0 = 0.f, q1 = 0.f, q2 = 0.f, q3 = 0.f;
#pragma unroll
    for (int cb = 0; cb < 8; ++cb) {
      int c = cb * 64 + cc;
      const float4 v = *(const float4*)(in + (size_t)c * HW + pos0 + p4);
      T[p4 + 0][c] = f2bf(v.x);
      T[p4 + 1][c] = f2bf(v.y);
      T[p4 + 2][c] = f2bf(v.z);
      T[p4 + 3][c] = f2bf(v.w);
      q0 += v.x * v.x; q1 += v.y * v.y; q2 += v.z * v.z; q3 += v.w * v.w;
    }
    sqa[cc][p4 + 0] = q0;
    sqa[cc][p4 + 1] = q1;
    sqa[cc][p4 + 2] = q2;
    sqa[cc][p4 + 3] = q3;
  }
  __syncthreads();
  if (t < 256) {
    int g2 = t >> 5, pos = t & 31;
    float v = 0.f;
#pragma unroll
    for (int r = 0; r < 8; ++r) v += sqa[g2 * 8 + r][pos];
    sq2[g2][pos] = v;
  }
  __syncthreads();
  if (t < 32) {
    float v = 0.f;
#pragma unroll
    for (int r = 0; r < 8; ++r) v += sq2[r][t];
    scl[t] = 1.f / fmaxf(sqrtf(v), 1e-12f);
  }
  __syncthreads();

  {
    int kb2 = t >> 6;    // 0..7
    int lane = t & 63;
    int lp = lane & 31;  // row within chunk
    int kh = lane >> 5;  // k-half
    float sc = scl[lp];
    int c0 = kb2 * 64 + kh * 32;
    unsigned char* o = out + (size_t)kb2 * 12288 + (size_t)R * 2048 + (size_t)lane * 16;
#pragma unroll
    for (int q = 0; q < 2; ++q) {
      const unsigned short* Tp = &T[lp][c0 + q * 16];
      uint4 u;
      u.x = __builtin_amdgcn_cvt_pk_fp8_f32(bf2f(Tp[0]) * sc, bf2f(Tp[1]) * sc, 0, false);
      u.x = __builtin_amdgcn_cvt_pk_fp8_f32(bf2f(Tp[2]) * sc, bf2f(Tp[3]) * sc, u.x, true);
      u.y = __builtin_amdgcn_cvt_pk_fp8_f32(bf2f(Tp[4]) * sc, bf2f(Tp[5]) * sc, 0, false);
      u.y = __builtin_amdgcn_cvt_pk_fp8_f32(bf2f(Tp[6]) * sc, bf2f(Tp[7]) * sc, u.y, true);
      u.z = __builtin_amdgcn_cvt_pk_fp8_f32(bf2f(Tp[8]) * sc, bf2f(Tp[9]) * sc, 0, false);
      u.z = __builtin_amdgcn_cvt_pk_fp8_f32(bf2f(Tp[10]) * sc, bf2f(Tp[11]) * sc, u.z, true);
      u.w = __builtin_amdgcn_cvt_pk_fp8_f32(bf2f(Tp[12]) * sc, bf2f(Tp[13]) * sc, 0, false);
      u.w = __builtin_amdgcn_cvt_pk_fp8_f32(bf2f(Tp[14]) * sc, bf2f(Tp[15]) * sc, u.w, true);
      *(uint4*)(o + q * 1024) = u;
    }
  }
}

// One block per (g,p). MX-scaled fp8 MFMA (unit scales, 2x non-scaled rate):
// 9 x mfma_scale_f32_32x32x64_f8f6f4 per kb2 per wave (was 72 x 16x16x32).
// Memory behavior byte-identical to r8: no LDS in K-loop, 12 x 1KB-contiguous
// wave-loads per kb2 direct global->VGPR, register double-buffered.
__global__ __launch_bounds__(256, 2) void qaconv_gemm(
    const unsigned char* __restrict__ ws, const float* __restrict__ fcw,
    const float* __restrict__ bnw, const float* __restrict__ bnb,
    const float* __restrict__ bnm, const float* __restrict__ bnv,
    const float* __restrict__ fcb, const float* __restrict__ lw,
    const float* __restrict__ lb, const float* __restrict__ lm,
    const float* __restrict__ lv, float* __restrict__ out) {
  int bid = blockIdx.x;
  int sb = bid >> 6, li = bid & 63;  // 8x8 supertiles for L2 locality
  int g = ((sb >> 3) << 3) + (li >> 3);
  int p = ((sb & 7) << 3) + (li & 7);
  const unsigned char* Bsrc = ws + (size_t)g * SLAB;         // galt[g] frags
  const unsigned char* Asrc = ws + (size_t)(GG + p) * SLAB;  // kern[p] frags

  __shared__ float colpart[2][HW];
  __shared__ float rowpart[2][HW];
  __shared__ float redbuf[4][2];

  int tid = threadIdx.x;
  int lane = tid & 63;
  int wave = tid >> 6;
  int wi = wave >> 1, wj = wave & 1;
  int l31 = lane & 31;

  floatx16 acc[3][3];
#pragma unroll
  for (int a = 0; a < 3; ++a)
#pragma unroll
    for (int c = 0; c < 3; ++c) acc[a][c] = (floatx16)(0.f);

  // frag (ta) lives at R = wi*3+ta; per-lane 32B = two 16B q-chunks 1KB apart
  const unsigned char* aP = Asrc + (size_t)(wi * 3) * 2048 + (size_t)lane * 16;
  const unsigned char* bP = Bsrc + (size_t)(wj * 3) * 2048 + (size_t)lane * 16;

  const int sc8 = 0x7f7f7f7f;  // E8M0 scales = 2^0

#define LOADF(AD, BD, KB)                                                      \
  do {                                                                         \
    _Pragma("unroll") for (int f_ = 0; f_ < 3; ++f_) {                         \
      AD##lo[f_] = *(const intx4*)(aP + (size_t)(KB)*12288 + f_ * 2048);       \
      AD##hi[f_] = *(const intx4*)(aP + (size_t)(KB)*12288 + f_ * 2048 + 1024);\
      BD##lo[f_] = *(const intx4*)(bP + (size_t)(KB)*12288 + f_ * 2048);       \
      BD##hi[f_] = *(const intx4*)(bP + (size_t)(KB)*12288 + f_ * 2048 + 1024);\
    }                                                                          \
  } while (0)

#define MFMAB(AD, BD)                                                          \
  do {                                                                         \
    intx8 A8[3], B8[3];                                                        \
    _Pragma("unroll") for (int f_ = 0; f_ < 3; ++f_) {                         \
      A8[f_][0] = AD##lo[f_].x; A8[f_][1] = AD##lo[f_].y;                      \
      A8[f_][2] = AD##lo[f_].z; A8[f_][3] = AD##lo[f_].w;                      \
      A8[f_][4] = AD##hi[f_].x; A8[f_][5] = AD##hi[f_].y;                      \
      A8[f_][6] = AD##hi[f_].z; A8[f_][7] = AD##hi[f_].w;                      \
      B8[f_][0] = BD##lo[f_].x; B8[f_][1] = BD##lo[f_].y;                      \
      B8[f_][2] = BD##lo[f_].z; B8[f_][3] = BD##lo[f_].w;                      \
      B8[f_][4] = BD##hi[f_].x; B8[f_][5] = BD##hi[f_].y;                      \
      B8[f_][6] = BD##hi[f_].z; B8[f_][7] = BD##hi[f_].w;                      \
    }                                                                          \
    _Pragma("unroll") for (int jt_ = 0; jt_ < 3; ++jt_)                        \
        _Pragma("unroll") for (int ta_ = 0; ta_ < 3; ++ta_)                    \
            acc[ta_][jt_] = __builtin_amdgcn_mfma_scale_f32_32x32x64_f8f6f4(   \
                A8[ta_], B8[jt_], acc[ta_][jt_], 0, 0, 0, sc8, 0, sc8);        \
  } while (0)

  intx4 aClo[3], aChi[3], bClo[3], bChi[3];
  intx4 aNlo[3], aNhi[3], bNlo[3], bNhi[3];
  LOADF(aC, bC, 0);
#pragma unroll 1
  for (int kb2 = 0; kb2 < 8; kb2 += 2) {
    LOADF(aN, bN, kb2 + 1);
    MFMAB(aC, bC);
    if (kb2 < 6) LOADF(aC, bC, kb2 + 2);
    MFMAB(aN, bN);
  }
#undef LOADF
#undef MFMAB

  // ---- epilogue: dual max-pool (r7-validated 32x32 C/D layout) ----
  // i = wi*96 + ta*32 + (r&3)+8*(r>>2)+4*(lane>>5) ; j = wj*96 + tc*32 + l31
#pragma unroll
  for (int tc = 0; tc < 3; ++tc) {
    float v = -3.4e38f;
#pragma unroll
    for (int ta = 0; ta < 3; ++ta)
#pragma unroll
      for (int r = 0; r < 16; ++r) v = fmaxf(v, acc[ta][tc][r]);
    v = fmaxf(v, __shfl_xor(v, 32, 64));
    if (lane < 32) colpart[wi][wj * 96 + tc * 32 + lane] = v;
  }
#pragma unroll
  for (int ta = 0; ta < 3; ++ta)
#pragma unroll
    for (int r = 0; r < 16; ++r) {
      float v = fmaxf(fmaxf(acc[ta][0][r], acc[ta][1][r]), acc[ta][2][r]);
      v = fmaxf(v, __shfl_xor(v, 1, 64));
      v = fmaxf(v, __shfl_xor(v, 2, 64));
      v = fmaxf(v, __shfl_xor(v, 4, 64));
      v = fmaxf(v, __shfl_xor(v, 8, 64));
      v = fmaxf(v, __shfl_xor(v, 16, 64));
      if (l31 == 0)
        rowpart[wj][wi * 96 + ta * 32 + (r & 3) + 8 * (r >> 2) + ((lane >> 5) << 2)] = v;
    }
  __syncthreads();

  // ---- fused BN -> fc -> lbn -> sigmoid ----
  float part = 0.f, wpart = 0.f;
  if (tid < HW) {
    float cmax = fmaxf(colpart[0][tid], colpart[1][tid]);  // score[j]
    float rmax = fmaxf(rowpart[0][tid], rowpart[1][tid]);  // score[192+i]
    float w1 = fcw[tid], w2 = fcw[HW + tid];
    part = cmax * w1 + rmax * w2;
    wpart = w1 + w2;
  }
#pragma unroll
  for (int off = 32; off > 0; off >>= 1) {
    part += __shfl_down(part, off, 64);
    wpart += __shfl_down(wpart, off, 64);
  }
  if (lane == 0) { redbuf[wave][0] = part; redbuf[wave][1] = wpart; }
  __syncthreads();
  if (tid == 0) {
    float s = redbuf[0][0] + redbuf[1][0] + redbuf[2][0] + redbuf[3][0];
    float wsum = redbuf[0][1] + redbuf[1][1] + redbuf[2][1] + redbuf[3][1];
    float bnA = bnw[0] * rsqrtf(bnv[0] + 1e-5f);
    float bnB = bnb[0] - bnm[0] * bnA;
    float sc = bnA * s + bnB * wsum + fcb[0];
    float lA = lw[0] * rsqrtf(lv[0] + 1e-5f);
    sc = (sc - lm[0]) * lA + lb[0];
    out[g * PP + p] = 1.f / (1.f + __expf(-sc * 0.1f));
  }
}

extern "C" void kernel_launch(void* const* d_in, const int* in_sizes, int n_in,
                              void* d_out, int out_size, void* d_ws, size_t ws_size,
                              hipStream_t stream) {
  const float* gal  = (const float*)d_in[0];
  const float* prob = (const float*)d_in[1];
  const float* bnw  = (const float*)d_in[2];
  const float* bnb  = (const float*)d_in[3];
  const float* bnm  = (const float*)d_in[4];
  const float* bnv  = (const float*)d_in[5];
  const float* fcw  = (const float*)d_in[6];
  const float* fcb  = (const float*)d_in[7];
  const float* lw   = (const float*)d_in[8];
  const float* lb   = (const float*)d_in[9];
  const float* lm   = (const float*)d_in[10];
  const float* lv   = (const float*)d_in[11];
  unsigned char* ws = (unsigned char*)d_ws;
  float* out = (float*)d_out;

  hipLaunchKernelGGL(norm_kernel, dim3(768), dim3(512), 0, stream, gal, prob, ws);
  hipLaunchKernelGGL(qaconv_gemm, dim3(GG * PP), dim3(256), 0, stream, ws, fcw,
                     bnw, bnb, bnm, bnv, fcb, lw, lb, lm, lv, out);
}

// Round 10
// 401.999 us; speedup vs baseline: 1.0190x; 1.0190x over previous
//
#include <hip/hip_runtime.h>

#define HW 192
#define DD 512
#define GG 64
#define PP 64
#define SLAB 98304  // 192*512 fp8 bytes per slab

typedef __attribute__((ext_vector_type(4))) int intx4;
typedef __attribute__((ext_vector_type(8))) int intx8;
typedef __attribute__((ext_vector_type(16))) float floatx16;

__device__ __forceinline__ unsigned short f2bf(float f) {
  unsigned int u = __float_as_uint(f);
  u += 0x7fffu + ((u >> 16) & 1u);
  return (unsigned short)(u >> 16);
}

__device__ __forceinline__ float bf2f(unsigned short u) {
  return __uint_as_float(((unsigned int)u) << 16);
}

// L2-normalize over channels -> fp8 e4m3, 32x32x64-fragment-linear ws layout
// (identical to r9, which validated numerically):
// ws[slab][kb2(8)][R(6)][q(2)][lane(64)][16B]
//   row = R*32 + (lane&31), khalf = lane>>5,
//   bytes = channels kb2*64 + khalf*32 + q*16 .. +15 of that row.
__global__ __launch_bounds__(512, 2) void norm_kernel(
    const float* __restrict__ gal, const float* __restrict__ prob,
    unsigned char* __restrict__ ws) {
  int b = blockIdx.x;  // 0..767
  int s = b / 6;       // slab 0..127
  int R = b - s * 6;   // 0..5
  const float* in = (s < GG) ? (gal + (size_t)s * DD * HW)
                             : (prob + (size_t)(s - GG) * DD * HW);
  unsigned char* out = ws + (size_t)s * SLAB;
  int pos0 = R * 32;
  int t = threadIdx.x;

  __shared__ unsigned short T[32][524];  // bf16 [pos][c], pad 524 -> <=2-way
  __shared__ float sqa[64][36];
  __shared__ float sq2[8][36];
  __shared__ float scl[32];

  {
    int cc = t >> 3;       // 0..63
    int p4 = (t & 7) * 4;  // 0,4,...,28
    float q0 = 0.f, q1 = 0.f, q2 = 0.f, q3 = 0.f;
#pragma unroll
    for (int cb = 0; cb < 8; ++cb) {
      int c = cb * 64 + cc;
      const float4 v = *(const float4*)(in + (size_t)c * HW + pos0 + p4);
      T[p4 + 0][c] = f2bf(v.x);
      T[p4 + 1][c] = f2bf(v.y);
      T[p4 + 2][c] = f2bf(v.z);
      T[p4 + 3][c] = f2bf(v.w);
      q0 += v.x * v.x; q1 += v.y * v.y; q2 += v.z * v.z; q3 += v.w * v.w;
    }
    sqa[cc][p4 + 0] = q0;
    sqa[cc][p4 + 1] = q1;
    sqa[cc][p4 + 2] = q2;
    sqa[cc][p4 + 3] = q3;
  }
  __syncthreads();
  if (t < 256) {
    int g2 = t >> 5, pos = t & 31;
    float v = 0.f;
#pragma unroll
    for (int r = 0; r < 8; ++r) v += sqa[g2 * 8 + r][pos];
    sq2[g2][pos] = v;
  }
  __syncthreads();
  if (t < 32) {
    float v = 0.f;
#pragma unroll
    for (int r = 0; r < 8; ++r) v += sq2[r][t];
    scl[t] = 1.f / fmaxf(sqrtf(v), 1e-12f);
  }
  __syncthreads();

  {
    int kb2 = t >> 6;    // 0..7
    int lane = t & 63;
    int lp = lane & 31;  // row within chunk
    int kh = lane >> 5;  // k-half
    float sc = scl[lp];
    int c0 = kb2 * 64 + kh * 32;
    unsigned char* o = out + (size_t)kb2 * 12288 + (size_t)R * 2048 + (size_t)lane * 16;
#pragma unroll
    for (int q = 0; q < 2; ++q) {
      const unsigned short* Tp = &T[lp][c0 + q * 16];
      uint4 u;
      u.x = __builtin_amdgcn_cvt_pk_fp8_f32(bf2f(Tp[0]) * sc, bf2f(Tp[1]) * sc, 0, false);
      u.x = __builtin_amdgcn_cvt_pk_fp8_f32(bf2f(Tp[2]) * sc, bf2f(Tp[3]) * sc, u.x, true);
      u.y = __builtin_amdgcn_cvt_pk_fp8_f32(bf2f(Tp[4]) * sc, bf2f(Tp[5]) * sc, 0, false);
      u.y = __builtin_amdgcn_cvt_pk_fp8_f32(bf2f(Tp[6]) * sc, bf2f(Tp[7]) * sc, u.y, true);
      u.z = __builtin_amdgcn_cvt_pk_fp8_f32(bf2f(Tp[8]) * sc, bf2f(Tp[9]) * sc, 0, false);
      u.z = __builtin_amdgcn_cvt_pk_fp8_f32(bf2f(Tp[10]) * sc, bf2f(Tp[11]) * sc, u.z, true);
      u.w = __builtin_amdgcn_cvt_pk_fp8_f32(bf2f(Tp[12]) * sc, bf2f(Tp[13]) * sc, 0, false);
      u.w = __builtin_amdgcn_cvt_pk_fp8_f32(bf2f(Tp[14]) * sc, bf2f(Tp[15]) * sc, u.w, true);
      *(uint4*)(o + q * 1024) = u;
    }
  }
}

// One block per (g,p). MX-scaled fp8 MFMA, unit E8M0 scales => 2x fp8 rate.
// r9 retry with spill-free operand marshalling: each intx8 operand is built
// ONCE at load time via shufflevector (no per-iteration A8/B8 rebuild).
// Peak live regs: 144 acc + 96 operand buffers + addr ~= 245 <= 256.
// Memory behavior identical to r8/r9: 12 x 1KB contiguous wave-loads per kb2,
// no LDS / no barriers in the K-loop, register double-buffered.
__global__ __launch_bounds__(256, 2) void qaconv_gemm(
    const unsigned char* __restrict__ ws, const float* __restrict__ fcw,
    const float* __restrict__ bnw, const float* __restrict__ bnb,
    const float* __restrict__ bnm, const float* __restrict__ bnv,
    const float* __restrict__ fcb, const float* __restrict__ lw,
    const float* __restrict__ lb, const float* __restrict__ lm,
    const float* __restrict__ lv, float* __restrict__ out) {
  int bid = blockIdx.x;
  int sb = bid >> 6, li = bid & 63;  // 8x8 supertiles for L2 locality
  int g = ((sb >> 3) << 3) + (li >> 3);
  int p = ((sb & 7) << 3) + (li & 7);
  const unsigned char* Bsrc = ws + (size_t)g * SLAB;         // galt[g] frags
  const unsigned char* Asrc = ws + (size_t)(GG + p) * SLAB;  // kern[p] frags

  __shared__ float colpart[2][HW];
  __shared__ float rowpart[2][HW];
  __shared__ float redbuf[4][2];

  int tid = threadIdx.x;
  int lane = tid & 63;
  int wave = tid >> 6;
  int wi = wave >> 1, wj = wave & 1;
  int l31 = lane & 31;

  floatx16 acc[3][3];
#pragma unroll
  for (int a = 0; a < 3; ++a)
#pragma unroll
    for (int c = 0; c < 3; ++c) acc[a][c] = (floatx16)(0.f);

  // frag (ta) lives at R = wi*3+ta; per-lane 32B = two 16B q-chunks 1KB apart
  const unsigned char* aP = Asrc + (size_t)(wi * 3) * 2048 + (size_t)lane * 16;
  const unsigned char* bP = Bsrc + (size_t)(wj * 3) * 2048 + (size_t)lane * 16;

  const int sc8 = 0x7f7f7f7f;  // E8M0 scales = 2^0

#define LOADF(AD, BD, KB)                                                    \
  do {                                                                       \
    _Pragma("unroll") for (int f_ = 0; f_ < 3; ++f_) {                       \
      intx4 alo = *(const intx4*)(aP + (size_t)(KB)*12288 + f_ * 2048);      \
      intx4 ahi = *(const intx4*)(aP + (size_t)(KB)*12288 + f_ * 2048 + 1024);\
      intx4 blo = *(const intx4*)(bP + (size_t)(KB)*12288 + f_ * 2048);      \
      intx4 bhi = *(const intx4*)(bP + (size_t)(KB)*12288 + f_ * 2048 + 1024);\
      AD[f_] = __builtin_shufflevector(alo, ahi, 0, 1, 2, 3, 4, 5, 6, 7);    \
      BD[f_] = __builtin_shufflevector(blo, bhi, 0, 1, 2, 3, 4, 5, 6, 7);    \
    }                                                                        \
  } while (0)

#define MFMAB(AD, BD)                                                        \
  do {                                                                       \
    _Pragma("unroll") for (int jt_ = 0; jt_ < 3; ++jt_)                      \
        _Pragma("unroll") for (int ta_ = 0; ta_ < 3; ++ta_)                  \
            acc[ta_][jt_] = __builtin_amdgcn_mfma_scale_f32_32x32x64_f8f6f4( \
                AD[ta_], BD[jt_], acc[ta_][jt_], 0, 0, 0, sc8, 0, sc8);      \
  } while (0)

  intx8 aC[3], bC[3], aN[3], bN[3];
  LOADF(aC, bC, 0);
#pragma unroll 1
  for (int kb2 = 0; kb2 < 8; kb2 += 2) {
    LOADF(aN, bN, kb2 + 1);
    MFMAB(aC, bC);
    if (kb2 < 6) LOADF(aC, bC, kb2 + 2);
    MFMAB(aN, bN);
  }
#undef LOADF
#undef MFMAB

  // ---- epilogue: dual max-pool (r7-validated 32x32 C/D layout) ----
  // i = wi*96 + ta*32 + (r&3)+8*(r>>2)+4*(lane>>5) ; j = wj*96 + tc*32 + l31
#pragma unroll
  for (int tc = 0; tc < 3; ++tc) {
    float v = -3.4e38f;
#pragma unroll
    for (int ta = 0; ta < 3; ++ta)
#pragma unroll
      for (int r = 0; r < 16; ++r) v = fmaxf(v, acc[ta][tc][r]);
    v = fmaxf(v, __shfl_xor(v, 32, 64));
    if (lane < 32) colpart[wi][wj * 96 + tc * 32 + lane] = v;
  }
#pragma unroll
  for (int ta = 0; ta < 3; ++ta)
#pragma unroll
    for (int r = 0; r < 16; ++r) {
      float v = fmaxf(fmaxf(acc[ta][0][r], acc[ta][1][r]), acc[ta][2][r]);
      v = fmaxf(v, __shfl_xor(v, 1, 64));
      v = fmaxf(v, __shfl_xor(v, 2, 64));
      v = fmaxf(v, __shfl_xor(v, 4, 64));
      v = fmaxf(v, __shfl_xor(v, 8, 64));
      v = fmaxf(v, __shfl_xor(v, 16, 64));
      if (l31 == 0)
        rowpart[wj][wi * 96 + ta * 32 + (r & 3) + 8 * (r >> 2) + ((lane >> 5) << 2)] = v;
    }
  __syncthreads();

  // ---- fused BN -> fc -> lbn -> sigmoid ----
  float part = 0.f, wpart = 0.f;
  if (tid < HW) {
    float cmax = fmaxf(colpart[0][tid], colpart[1][tid]);  // score[j]
    float rmax = fmaxf(rowpart[0][tid], rowpart[1][tid]);  // score[192+i]
    float w1 = fcw[tid], w2 = fcw[HW + tid];
    part = cmax * w1 + rmax * w2;
    wpart = w1 + w2;
  }
#pragma unroll
  for (int off = 32; off > 0; off >>= 1) {
    part += __shfl_down(part, off, 64);
    wpart += __shfl_down(wpart, off, 64);
  }
  if (lane == 0) { redbuf[wave][0] = part; redbuf[wave][1] = wpart; }
  __syncthreads();
  if (tid == 0) {
    float s = redbuf[0][0] + redbuf[1][0] + redbuf[2][0] + redbuf[3][0];
    float wsum = redbuf[0][1] + redbuf[1][1] + redbuf[2][1] + redbuf[3][1];
    float bnA = bnw[0] * rsqrtf(bnv[0] + 1e-5f);
    float bnB = bnb[0] - bnm[0] * bnA;
    float sc = bnA * s + bnB * wsum + fcb[0];
    float lA = lw[0] * rsqrtf(lv[0] + 1e-5f);
    sc = (sc - lm[0]) * lA + lb[0];
    out[g * PP + p] = 1.f / (1.f + __expf(-sc * 0.1f));
  }
}

extern "C" void kernel_launch(void* const* d_in, const int* in_sizes, int n_in,
                              void* d_out, int out_size, void* d_ws, size_t ws_size,
                              hipStream_t stream) {
  const float* gal  = (const float*)d_in[0];
  const float* prob = (const float*)d_in[1];
  const float* bnw  = (const float*)d_in[2];
  const float* bnb  = (const float*)d_in[3];
  const float* bnm  = (const float*)d_in[4];
  const float* bnv  = (const float*)d_in[5];
  const float* fcw  = (const float*)d_in[6];
  const float* fcb  = (const float*)d_in[7];
  const float* lw   = (const float*)d_in[8];
  const float* lb   = (const float*)d_in[9];
  const float* lm   = (const float*)d_in[10];
  const float* lv   = (const float*)d_in[11];
  unsigned char* ws = (unsigned char*)d_ws;
  float* out = (float*)d_out;

  hipLaunchKernelGGL(norm_kernel, dim3(768), dim3(512), 0, stream, gal, prob, ws);
  hipLaunchKernelGGL(qaconv_gemm, dim3(GG * PP), dim3(256), 0, stream, ws, fcw,
                     bnw, bnb, bnm, bnv, fcb, lw, lb, lm, lv, out);
}

// Round 11
// 193.474 us; speedup vs baseline: 2.1174x; 2.0778x over previous
//
#include <hip/hip_runtime.h>

#define HW 192
#define DD 512
#define GG 64
#define PP 64
#define SLAB 98304  // 192*512 i8 bytes per slab

typedef __attribute__((ext_vector_type(4))) int intx4;

__device__ __forceinline__ unsigned int pk4(float a, float b, float c, float d) {
  int qa = (int)rintf(a), qb = (int)rintf(b), qc = (int)rintf(c), qd = (int)rintf(d);
  return (unsigned)(qa & 255) | ((unsigned)(qb & 255) << 8) |
         ((unsigned)(qc & 255) << 16) | ((unsigned)(qd & 255) << 24);
}

// L2-normalize over channels -> int8 (q = rint(127*v)), fragment-linear ws:
// ws[slab][kb2(8)][R(12)][lane(64)][16B]
//   pos = R*16 + (lane&15), bytes = channels kb2*64 + (lane>>4)*16 .. +15.
// This is the per-lane operand order of mfma_i32_16x16x64_i8 (16B/lane,
// k = quad*16 + j — natural extension of the HW-validated 16x16x32 family),
// so the GEMM loads fragments straight from global (1KB contiguous per
// wave-load). Block = (slab, 16-pos chunk), 512 threads; r8-proven structure.
__global__ __launch_bounds__(512, 2) void norm_kernel(
    const float* __restrict__ gal, const float* __restrict__ prob,
    unsigned char* __restrict__ ws) {
  int b = blockIdx.x;  // 0..1535
  int s = b / 12;      // slab 0..127
  int q = b - s * 12;  // pos chunk (= R) 0..11
  const float* in = (s < GG) ? (gal + (size_t)s * DD * HW)
                             : (prob + (size_t)(s - GG) * DD * HW);
  unsigned char* out = ws + (size_t)s * SLAB;
  int pos0 = q * 16;
  int t = threadIdx.x;

  __shared__ float T[16][524];   // 33.5 KB, [pos][c]
  __shared__ float sqa[128][17];
  __shared__ float sq2[16][17];
  __shared__ float scl[16];

  {
    int cq = t >> 2;   // 0..127
    int quad = t & 3;  // 0..3
    float p0 = 0.f, p1 = 0.f, p2 = 0.f, p3 = 0.f;
#pragma unroll
    for (int cb = 0; cb < 4; ++cb) {
      int c = cb * 128 + cq;
      const float4 v = *(const float4*)(in + (size_t)c * HW + pos0 + quad * 4);
      T[quad * 4 + 0][c] = v.x;
      T[quad * 4 + 1][c] = v.y;
      T[quad * 4 + 2][c] = v.z;
      T[quad * 4 + 3][c] = v.w;
      p0 += v.x * v.x; p1 += v.y * v.y; p2 += v.z * v.z; p3 += v.w * v.w;
    }
    sqa[cq][quad * 4 + 0] = p0;
    sqa[cq][quad * 4 + 1] = p1;
    sqa[cq][quad * 4 + 2] = p2;
    sqa[cq][quad * 4 + 3] = p3;
  }
  __syncthreads();
  if (t < 256) {
    int g2 = t >> 4, pos = t & 15;
    float v = 0.f;
#pragma unroll
    for (int r = 0; r < 8; ++r) v += sqa[g2 * 8 + r][pos];
    sq2[g2][pos] = v;
  }
  __syncthreads();
  if (t < 16) {
    float v = 0.f;
#pragma unroll
    for (int r = 0; r < 16; ++r) v += sq2[r][t];
    scl[t] = 1.f / fmaxf(sqrtf(v), 1e-12f);
  }
  __syncthreads();

  {
    int kb2 = t >> 6;    // 0..7 (uniform per wave)
    int lane = t & 63;
    int l4 = lane >> 4;  // k-quarter 0..3
    int pos = lane & 15; // 0..15
    float sc = scl[pos] * 127.f;
    int base = kb2 * 64 + l4 * 16;
    const float4 r0 = *(const float4*)&T[pos][base + 0];
    const float4 r1 = *(const float4*)&T[pos][base + 4];
    const float4 r2 = *(const float4*)&T[pos][base + 8];
    const float4 r3 = *(const float4*)&T[pos][base + 12];
    uint4 u;
    u.x = pk4(r0.x * sc, r0.y * sc, r0.z * sc, r0.w * sc);
    u.y = pk4(r1.x * sc, r1.y * sc, r1.z * sc, r1.w * sc);
    u.z = pk4(r2.x * sc, r2.y * sc, r2.z * sc, r2.w * sc);
    u.w = pk4(r3.x * sc, r3.y * sc, r3.z * sc, r3.w * sc);
    *(uint4*)(out + (size_t)kb2 * 12288 + (size_t)q * 1024 + (size_t)lane * 16) = u;
  }
}

// One block per (g,p), int8 via mfma_i32_16x16x64_i8 (2x K per inst vs fp8
// 16x16x32 => MFMA-issue term halves; ordinary v4i32 operands => no spills,
// unlike the scaled-MFMA attempts r9/r10). Memory behavior byte-identical to
// r8: no LDS / no barriers in K-loop, 12 x 1KB contiguous wave-loads per kb2,
// register double-buffered. Epilogue: max-pool in int32 (monotone), one
// float convert * (1/127^2) at the end.
__global__ __launch_bounds__(256, 2) void qaconv_gemm(
    const unsigned char* __restrict__ ws, const float* __restrict__ fcw,
    const float* __restrict__ bnw, const float* __restrict__ bnb,
    const float* __restrict__ bnm, const float* __restrict__ bnv,
    const float* __restrict__ fcb, const float* __restrict__ lw,
    const float* __restrict__ lb, const float* __restrict__ lm,
    const float* __restrict__ lv, float* __restrict__ out) {
  int bid = blockIdx.x;
  int sb = bid >> 6, li = bid & 63;  // 8x8 supertiles for L2 locality
  int g = ((sb >> 3) << 3) + (li >> 3);
  int p = ((sb & 7) << 3) + (li & 7);
  const unsigned char* Bsrc = ws + (size_t)g * SLAB;         // galt[g] frags
  const unsigned char* Asrc = ws + (size_t)(GG + p) * SLAB;  // kern[p] frags

  __shared__ float colpart[2][HW];
  __shared__ float rowpart[2][HW];
  __shared__ float redbuf[4][2];

  int tid = threadIdx.x;
  int lane = tid & 63;
  int wave = tid >> 6;
  int wi = wave >> 1, wj = wave & 1;
  int l15 = lane & 15, l4 = lane >> 4;

  intx4 acc[6][6];
#pragma unroll
  for (int a = 0; a < 6; ++a)
#pragma unroll
    for (int c = 0; c < 6; ++c) acc[a][c] = (intx4){0, 0, 0, 0};

  // frag (it) lives at R = wi*6+it (A) / wj*6+jt (B)
  const unsigned char* aP = Asrc + (size_t)(wi * 6) * 1024 + (size_t)lane * 16;
  const unsigned char* bP = Bsrc + (size_t)(wj * 6) * 1024 + (size_t)lane * 16;

#define LOADF(AD, BD, KB)                                                 \
  do {                                                                    \
    _Pragma("unroll") for (int it_ = 0; it_ < 6; ++it_) {                 \
      AD[it_] = *(const intx4*)(aP + (size_t)(KB)*12288 + it_ * 1024);    \
      BD[it_] = *(const intx4*)(bP + (size_t)(KB)*12288 + it_ * 1024);    \
    }                                                                     \
  } while (0)

#define MFMAB(AD, BD)                                                     \
  do {                                                                    \
    _Pragma("unroll") for (int jt_ = 0; jt_ < 6; ++jt_) {                 \
      intx4 bb = BD[jt_];                                                 \
      _Pragma("unroll") for (int it_ = 0; it_ < 6; ++it_)                 \
          acc[it_][jt_] = __builtin_amdgcn_mfma_i32_16x16x64_i8(          \
              AD[it_], bb, acc[it_][jt_], 0, 0, 0);                       \
    }                                                                     \
  } while (0)

  intx4 aC[6], bC[6], aN[6], bN[6];
  LOADF(aC, bC, 0);
#pragma unroll 1
  for (int kb2 = 0; kb2 < 8; kb2 += 2) {
    LOADF(aN, bN, kb2 + 1);
    MFMAB(aC, bC);
    if (kb2 < 6) LOADF(aC, bC, kb2 + 2);
    MFMAB(aN, bN);
  }
#undef LOADF
#undef MFMAB

  // ---- epilogue: dual max-pool in int32 ----
  // C/D layout: i = wi*96 + it*16 + l4*4 + r ; j = wj*96 + jt*16 + l15
  const float inv = 1.f / 16129.f;  // 1/127^2
  int cm[6];
  int rm[6][4];
#pragma unroll
  for (int jt = 0; jt < 6; ++jt) cm[jt] = -2147483647;
#pragma unroll
  for (int it = 0; it < 6; ++it)
#pragma unroll
    for (int r = 0; r < 4; ++r) rm[it][r] = -2147483647;
#pragma unroll
  for (int it = 0; it < 6; ++it)
#pragma unroll
    for (int jt = 0; jt < 6; ++jt)
#pragma unroll
      for (int r = 0; r < 4; ++r) {
        int v = acc[it][jt][r];
        cm[jt] = max(cm[jt], v);
        rm[it][r] = max(rm[it][r], v);
      }

#pragma unroll
  for (int jt = 0; jt < 6; ++jt) {
    int v = cm[jt];
    v = max(v, __shfl_xor(v, 16, 64));
    v = max(v, __shfl_xor(v, 32, 64));
    if (lane < 16) colpart[wi][wj * 96 + jt * 16 + lane] = (float)v * inv;
  }
#pragma unroll
  for (int it = 0; it < 6; ++it)
#pragma unroll
    for (int r = 0; r < 4; ++r) {
      int v = rm[it][r];
      v = max(v, __shfl_xor(v, 1, 64));
      v = max(v, __shfl_xor(v, 2, 64));
      v = max(v, __shfl_xor(v, 4, 64));
      v = max(v, __shfl_xor(v, 8, 64));
      if (l15 == 0) rowpart[wj][wi * 96 + it * 16 + l4 * 4 + r] = (float)v * inv;
    }
  __syncthreads();

  // ---- fused BN -> fc -> lbn -> sigmoid ----
  float part = 0.f, wpart = 0.f;
  if (tid < HW) {
    float cmax = fmaxf(colpart[0][tid], colpart[1][tid]);  // score[j]
    float rmax = fmaxf(rowpart[0][tid], rowpart[1][tid]);  // score[192+i]
    float w1 = fcw[tid], w2 = fcw[HW + tid];
    part = cmax * w1 + rmax * w2;
    wpart = w1 + w2;
  }
#pragma unroll
  for (int off = 32; off > 0; off >>= 1) {
    part += __shfl_down(part, off, 64);
    wpart += __shfl_down(wpart, off, 64);
  }
  if (lane == 0) { redbuf[wave][0] = part; redbuf[wave][1] = wpart; }
  __syncthreads();
  if (tid == 0) {
    float s = redbuf[0][0] + redbuf[1][0] + redbuf[2][0] + redbuf[3][0];
    float wsum = redbuf[0][1] + redbuf[1][1] + redbuf[2][1] + redbuf[3][1];
    float bnA = bnw[0] * rsqrtf(bnv[0] + 1e-5f);
    float bnB = bnb[0] - bnm[0] * bnA;
    float sc = bnA * s + bnB * wsum + fcb[0];
    float lA = lw[0] * rsqrtf(lv[0] + 1e-5f);
    sc = (sc - lm[0]) * lA + lb[0];
    out[g * PP + p] = 1.f / (1.f + __expf(-sc * 0.1f));
  }
}

extern "C" void kernel_launch(void* const* d_in, const int* in_sizes, int n_in,
                              void* d_out, int out_size, void* d_ws, size_t ws_size,
                              hipStream_t stream) {
  const float* gal  = (const float*)d_in[0];
  const float* prob = (const float*)d_in[1];
  const float* bnw  = (const float*)d_in[2];
  const float* bnb  = (const float*)d_in[3];
  const float* bnm  = (const float*)d_in[4];
  const float* bnv  = (const float*)d_in[5];
  const float* fcw  = (const float*)d_in[6];
  const float* fcb  = (const float*)d_in[7];
  const float* lw   = (const float*)d_in[8];
  const float* lb   = (const float*)d_in[9];
  const float* lm   = (const float*)d_in[10];
  const float* lv   = (const float*)d_in[11];
  unsigned char* ws = (unsigned char*)d_ws;
  float* out = (float*)d_out;

  hipLaunchKernelGGL(norm_kernel, dim3(1536), dim3(512), 0, stream, gal, prob, ws);
  hipLaunchKernelGGL(qaconv_gemm, dim3(GG * PP), dim3(256), 0, stream, ws, fcw,
                     bnw, bnb, bnm, bnv, fcb, lw, lb, lm, lv, out);
}